// Round 1
// baseline (7701.714 us; speedup 1.0000x reference)
//
#include <hip/hip_runtime.h>
#include <hip/hip_bf16.h>

#define DIMC 180
#define NHEADS 6
#define HDIM 30
#define NTOK 64
#define NWIN 4096
#define OUT1_ELEMS (NWIN * NTOK * DIMC)  // 47185920 floats per output tensor

typedef __hip_bfloat16 bf16;

__device__ __forceinline__ float bf2f(bf16 v) { return __bfloat162float(v); }
__device__ __forceinline__ bf16 f2bf(float v) { return __float2bfloat16(v); }

__device__ __forceinline__ float wave_reduce_max(float v) {
#pragma unroll
    for (int m = 32; m >= 1; m >>= 1) v = fmaxf(v, __shfl_xor(v, m, 64));
    return v;
}
__device__ __forceinline__ float wave_reduce_sum(float v) {
#pragma unroll
    for (int m = 32; m >= 1; m >>= 1) v += __shfl_xor(v, m, 64);
    return v;
}

// Kernel A: per (window, branch). Computes sigmoid gate projection (staged as
// bf16 into the out1 half of d_out) and QKV + attention output (staged as bf16
// into the out2 half of d_out).
__global__ __launch_bounds__(256) void attn_kernel(
    const float* __restrict__ e, const float* __restrict__ b,
    const float* __restrict__ mask, const float* __restrict__ rpb_table,
    const int* __restrict__ rpi,
    const float* __restrict__ Wqkv_e, const float* __restrict__ bqkv_e,
    const float* __restrict__ Wqkv_b, const float* __restrict__ bqkv_b,
    const float* __restrict__ Wpe_s, const float* __restrict__ bpe_s,
    const float* __restrict__ Wpb_s, const float* __restrict__ bpb_s,
    float* __restrict__ d_out)
{
    const int w   = blockIdx.x;
    const int br  = blockIdx.y;
    const int tid = threadIdx.x;
    const int lane = tid & 63;
    const int jj = __builtin_amdgcn_readfirstlane(tid >> 6);  // wave id 0..3 (uniform)

    const float* x    = br ? b      : e;
    const float* Wqkv = br ? Wqkv_b : Wqkv_e;
    const float* bqkv = br ? bqkv_b : bqkv_e;
    const float* Wps  = br ? Wpb_s  : Wpe_s;
    const float* bps  = br ? bpb_s  : bpe_s;

    __shared__ bf16  sX[NTOK * DIMC];   // 23040 B, x tile
    __shared__ bf16  sQ[NTOK * 62];     // 7936 B  (2 heads x 30, padded to 62 -> 31-dword stride)
    __shared__ bf16  sK[NTOK * 62];
    __shared__ bf16  sV[NTOK * 62];
    __shared__ float sS[NTOK * NTOK];   // 16384 B scores/probs
    // total 63232 B

    for (int idx = tid; idx < NTOK * DIMC; idx += 256)
        sX[idx] = f2bf(x[(size_t)w * (NTOK * DIMC) + idx]);
    __syncthreads();

    // ---- sigmoid gate projection: sigmoid(x @ Wps + bps) -> out1-half staging
    bf16* sig_stage = reinterpret_cast<bf16*>(d_out);
    {
        const int i = lane;          // row
        const int colb = jj * 45;    // wave-uniform column group
        float acc[45];
#pragma unroll
        for (int m = 0; m < 45; ++m) acc[m] = bps[colb + m];
        for (int k = 0; k < DIMC; ++k) {
            float xk = bf2f(sX[i * DIMC + k]);
            const float* wr = Wps + k * DIMC + colb;   // uniform address -> s_load
#pragma unroll
            for (int m = 0; m < 45; ++m) acc[m] = fmaf(xk, wr[m], acc[m]);
        }
        size_t base = (size_t)w * 23040 + (size_t)br * 11520 + (size_t)i * DIMC + colb;
#pragma unroll
        for (int m = 0; m < 45; ++m) {
            float s = 1.f / (1.f + __expf(-acc[m]));
            sig_stage[base + m] = f2bf(s);
        }
    }

    const float scale = 0.18257418583505536f;  // 30^-0.5
    bf16* out_stage = reinterpret_cast<bf16*>(d_out + OUT1_ELEMS);

    // process heads in pairs (2 heads => 60 cols per q/k/v section => 15 cols/wave)
    for (int g = 0; g < 3; ++g) {
        const int i = lane;
        for (int s = 0; s < 3; ++s) {     // 0=q, 1=k, 2=v
            const int colb = s * DIMC + g * 60 + jj * 15;  // global col in [0,540)
            float acc[15];
#pragma unroll
            for (int m = 0; m < 15; ++m) acc[m] = bqkv[colb + m];
            for (int k = 0; k < DIMC; ++k) {
                float xk = bf2f(sX[i * DIMC + k]);
                const float* wr = Wqkv + k * 540 + colb;
#pragma unroll
                for (int m = 0; m < 15; ++m) acc[m] = fmaf(xk, wr[m], acc[m]);
            }
            bf16* dst = (s == 0) ? sQ : ((s == 1) ? sK : sV);
            const int lc = jj * 15;
#pragma unroll
            for (int m = 0; m < 15; ++m) dst[i * 62 + lc + m] = f2bf(acc[m]);
        }
        __syncthreads();

        for (int h2 = 0; h2 < 2; ++h2) {
            const int h = 2 * g + h2;
            // scores + softmax: wave jj owns rows (4*e + jj); lane = key index j
            const int j = lane;
            for (int eidx = 0; eidx < 16; ++eidx) {
                const int row = 4 * eidx + jj;
                float dot = 0.f;
#pragma unroll
                for (int d = 0; d < HDIM; ++d)
                    dot += bf2f(sQ[row * 62 + h2 * 30 + d]) * bf2f(sK[j * 62 + h2 * 30 + d]);
                float sc = scale * dot
                         + rpb_table[rpi[row * 64 + j] * NHEADS + h]
                         + mask[(size_t)w * 4096 + row * 64 + j];
                float mx  = wave_reduce_max(sc);
                float p   = __expf(sc - mx);
                float sum = wave_reduce_sum(p);
                sS[row * 64 + j] = p / sum;
            }
            __syncthreads();
            // P @ V -> attention output chunk, staged bf16 into out2 half
            for (int ent = tid; ent < NTOK * HDIM; ent += 256) {
                const int row = ent / HDIM;
                const int d   = ent % HDIM;
                float o = 0.f;
#pragma unroll
                for (int jx = 0; jx < 64; ++jx)
                    o += sS[row * 64 + jx] * bf2f(sV[jx * 62 + h2 * 30 + d]);
                out_stage[(size_t)w * 23040 + br * 11520 + row * DIMC + h * HDIM + d] = f2bf(o);
            }
            __syncthreads();
        }
    }
}

// Kernel B: per window. Reads staged oe/ob (out2 half) and es/bs (out1 half),
// computes out1 = [oe*es, ob*es] @ Wpe + bpe and out2 = [oe*bs, ob*bs] @ Wpb + bpb,
// overwriting both halves of d_out with the final f32 results.
__global__ __launch_bounds__(256) void final_kernel(
    const float* __restrict__ Wpe, const float* __restrict__ bpe,
    const float* __restrict__ Wpb, const float* __restrict__ bpb,
    float* __restrict__ d_out)
{
    const int w   = blockIdx.x;
    const int tid = threadIdx.x;
    const int lane = tid & 63;
    const int jj = __builtin_amdgcn_readfirstlane(tid >> 6);

    __shared__ bf16 sO[2 * NTOK * DIMC];   // oe then ob: 46080 B
    __shared__ bf16 sSig[2 * NTOK * 36];   // es chunk then bs chunk: 9216 B

    const bf16* out_stage = reinterpret_cast<const bf16*>(d_out + OUT1_ELEMS);
    const bf16* sig_stage = reinterpret_cast<const bf16*>(d_out);

    for (int idx = tid; idx < 2 * NTOK * DIMC; idx += 256)
        sO[idx] = out_stage[(size_t)w * 23040 + idx];
    __syncthreads();

    const int i = lane;
    const int colb = jj * 45;
    float acc1[45], acc2[45];
#pragma unroll
    for (int m = 0; m < 45; ++m) { acc1[m] = bpe[colb + m]; acc2[m] = bpb[colb + m]; }

    for (int cc = 0; cc < DIMC; cc += 36) {
        for (int idx = tid; idx < 2 * NTOK * 36; idx += 256) {
            int which = idx / (NTOK * 36);
            int r  = idx % (NTOK * 36);
            int i2 = r / 36, c2 = r % 36;
            sSig[idx] = sig_stage[(size_t)w * 23040 + which * 11520 + i2 * DIMC + cc + c2];
        }
        __syncthreads();
        for (int c2 = 0; c2 < 36; ++c2) {
            const int c = cc + c2;
            float oe = bf2f(sO[i * DIMC + c]);
            float ob = bf2f(sO[NTOK * DIMC + i * DIMC + c]);
            float es = bf2f(sSig[i * 36 + c2]);
            float bs = bf2f(sSig[NTOK * 36 + i * 36 + c2]);
            float p1 = oe * es, p2 = ob * es, p3 = oe * bs, p4 = ob * bs;
            const float* w1 = Wpe + (size_t)c * DIMC + colb;
            const float* w2 = Wpe + (size_t)(DIMC + c) * DIMC + colb;
            const float* w3 = Wpb + (size_t)c * DIMC + colb;
            const float* w4 = Wpb + (size_t)(DIMC + c) * DIMC + colb;
#pragma unroll
            for (int m = 0; m < 45; ++m) {
                acc1[m] = fmaf(p1, w1[m], fmaf(p2, w2[m], acc1[m]));
                acc2[m] = fmaf(p3, w3[m], fmaf(p4, w4[m], acc2[m]));
            }
        }
        __syncthreads();
    }

    size_t o1 = (size_t)w * 11520 + (size_t)i * DIMC + colb;
#pragma unroll
    for (int m = 0; m < 45; ++m) {
        d_out[o1 + m]              = acc1[m];
        d_out[OUT1_ELEMS + o1 + m] = acc2[m];
    }
}

extern "C" void kernel_launch(void* const* d_in, const int* in_sizes, int n_in,
                              void* d_out, int out_size, void* d_ws, size_t ws_size,
                              hipStream_t stream) {
    const float* e      = (const float*)d_in[0];
    const float* b      = (const float*)d_in[1];
    const float* mask   = (const float*)d_in[2];
    const float* rpb    = (const float*)d_in[3];
    const int*   rpi    = (const int*)  d_in[4];
    const float* Wqkv_e = (const float*)d_in[5];
    const float* bqkv_e = (const float*)d_in[6];
    const float* Wqkv_b = (const float*)d_in[7];
    const float* bqkv_b = (const float*)d_in[8];
    const float* Wpe_s  = (const float*)d_in[9];
    const float* bpe_s  = (const float*)d_in[10];
    const float* Wpb_s  = (const float*)d_in[11];
    const float* bpb_s  = (const float*)d_in[12];
    const float* Wpe    = (const float*)d_in[13];
    const float* bpe    = (const float*)d_in[14];
    const float* Wpb    = (const float*)d_in[15];
    const float* bpb    = (const float*)d_in[16];
    float* out = (float*)d_out;

    attn_kernel<<<dim3(NWIN, 2), dim3(256), 0, stream>>>(
        e, b, mask, rpb, rpi, Wqkv_e, bqkv_e, Wqkv_b, bqkv_b,
        Wpe_s, bpe_s, Wpb_s, bpb_s, out);
    final_kernel<<<dim3(NWIN), dim3(256), 0, stream>>>(
        Wpe, bpe, Wpb, bpb, out);
}